// Round 1
// baseline (237.399 us; speedup 1.0000x reference)
//
#include <hip/hip_runtime.h>
#include <stdint.h>

// MFMA fragment types (gfx950)
typedef __attribute__((ext_vector_type(8))) short short8;  // 8 bf16 = 4 VGPRs
typedef __attribute__((ext_vector_type(4))) float f32x4;   // 4 fp32 acc / vec load

static_assert(sizeof(short8) == 16, "frag size");

__device__ __forceinline__ uint16_t f2bf(float f) {
  uint32_t u = __builtin_bit_cast(uint32_t, f);
  u += 0x7fffu + ((u >> 16) & 1u);
  return (uint16_t)(u >> 16);
}

__device__ __forceinline__ void gload_lds16(const void* g, void* lds_wave_base) {
  // async global->LDS, 16B/lane; LDS dst = wave-uniform base + lane*16
  __builtin_amdgcn_global_load_lds(
      (__attribute__((address_space(1))) void*)(void*)(g),
      (__attribute__((address_space(3))) void*)(lds_wave_base),
      16, 0, 0);
}

// Swizzle convention (all bf16 staging): within each 64-elem K-group, 16B
// chunk c of row r is stored at chunk c ^ (r&7) (XOR touches bits 0-2 only,
// composing transparently with any BK). DMA stages tiles verbatim; fragment
// reads at chunk (h*4+q)^(r&7) are conflict-free ds_read_b128.

// ---------------------------------------------------------------------------
// quant: dwT[o][i] = ternary(weight[i][o]) in {-1,0,+1} bf16, swizzled.
// ---------------------------------------------------------------------------
__global__ __launch_bounds__(256) void quant_kernel(const float* __restrict__ w,
                                                    uint16_t* __restrict__ dwT) {
  const int o = blockIdx.x, i = threadIdx.x;
  const float v = w[i * 256 + o];
  const float t = (v > 0.01f) ? 1.0f : ((v < -0.01f) ? -1.0f : 0.0f);
  dwT[o * 256 + (i ^ ((o & 7) << 3))] = f2bf(t);
}

// ---------------------------------------------------------------------------
// support (SINGLE-PASS K=256): spt[o][g] = bf16(0.01 * sum_i x[g][i]*tern[i][o])
// Tile [64 g][64 o], full K staged once (A 32 KB + B 32 KB = 64 KB LDS,
// 2 blocks/CU). Grid 1024 = 256 g-tiles x 4 o-tiles. 3 barriers/block total.
// Wave w: g-rows [16w,16w+16) -> acc[4] (o-tiles).
// ---------------------------------------------------------------------------
#define SB_A 0       // [64 g][256 i] bf16 swizzled, 32768 B (reused in epilogue)
#define SB_B 32768   // [64 o][256 i] bf16 swizzled, 32768 B

__global__ __launch_bounds__(256) void support_kernel(const float* __restrict__ x,
                                                      const uint16_t* __restrict__ dwT,
                                                      uint16_t* __restrict__ spt) {
  __shared__ __align__(16) unsigned char smem[65536];
  const int t = threadIdx.x, lane = t & 63, w = t >> 6;
  const int r = lane & 15, q = lane >> 4;
  const int g0 = (blockIdx.x & 255) * 64;
  const int o0 = (blockIdx.x >> 8) * 64;

  // stage A: x [64 g][256 i] fp32 -> bf16, packed b128 swizzled writes
#pragma unroll
  for (int j = 0; j < 8; ++j) {
    const int id = j * 256 + t;              // 64 rows x 32 chunks = 2048 ids
    const int row = id >> 5, c = id & 31;
    const float* p = x + (size_t)(g0 + row) * 256 + c * 8;
    const f32x4 v0 = *(const f32x4*)p;
    const f32x4 v1 = *(const f32x4*)(p + 4);
    uint4 u;
    u.x = (uint32_t)f2bf(v0.x) | ((uint32_t)f2bf(v0.y) << 16);
    u.y = (uint32_t)f2bf(v0.z) | ((uint32_t)f2bf(v0.w) << 16);
    u.z = (uint32_t)f2bf(v1.x) | ((uint32_t)f2bf(v1.y) << 16);
    u.w = (uint32_t)f2bf(v1.z) | ((uint32_t)f2bf(v1.w) << 16);
    *(uint4*)(smem + SB_A + row * 512 + ((c ^ (row & 7)) << 4)) = u;
  }
  // stage B: dwT rows [o0,o0+64) full K, verbatim DMA (pre-swizzled)
#pragma unroll
  for (int j = 0; j < 8; ++j) {
    const int id = j * 256 + t, row = id >> 5, c = id & 31;
    gload_lds16(dwT + (size_t)(o0 + row) * 256 + c * 8,
                smem + SB_B + (size_t)(j * 256 + w * 64) * 16);
  }
  __syncthreads();

  f32x4 acc[4] = {};
#pragma unroll
  for (int h = 0; h < 8; ++h) {              // K=256 in 8 steps of 32
    short8 av, bv[4];
    const int pc = (((h * 4 + q) ^ (r & 7)) << 4);
    av = *(const short8*)(smem + SB_A + (16 * w + r) * 512 + pc);
#pragma unroll
    for (int ni = 0; ni < 4; ++ni)
      bv[ni] = *(const short8*)(smem + SB_B + (16 * ni + r) * 512 + pc);
#pragma unroll
    for (int ni = 0; ni < 4; ++ni)
      acc[ni] = __builtin_amdgcn_mfma_f32_16x16x32_bf16(av, bv[ni], acc[ni], 0, 0, 0);
  }
  __syncthreads();   // all waves' LDS reads done before transpose overwrite

  // epilogue: transpose buffer [64 o][64 g] bf16 (8 KB, reuses SB_A region)
#pragma unroll
  for (int ni = 0; ni < 4; ++ni) {
    const int ol = 16 * ni + r;              // C col = o
#pragma unroll
    for (int reg = 0; reg < 4; ++reg) {
      const int gl = 16 * w + 4 * q + reg;   // C row = g
      const int gsw = gl ^ ((ol & 7) << 3);  // global col swizzle
      *(uint16_t*)(smem + (ol * 64 + gsw) * 2) = f2bf(acc[ni][reg] * 0.01f);
    }
  }
  __syncthreads();
  // copy out: 64 rows x 8 chunks of 16 B, coalesced dwordx4
#pragma unroll
  for (int it = 0; it < 2; ++it) {
    const int id = it * 256 + t, row = id >> 3, cc = id & 7;
    const uint4 u = *(const uint4*)(smem + (row * 64 + cc * 8) * 2);
    *(uint4*)(spt + (size_t)(o0 + row) * 16384 + g0 + cc * 8) = u;
  }
}

// ---------------------------------------------------------------------------
// main v2 (2-phase pipelined, BK=64, dbuf): out = relu(adj @ support + bias)
// Tile [32 n][256 o], K=2048 in BK=64 steps (32 iters), double-buffered LDS
// (A 2x4KB + B 2x32KB = 72 KB -> 2 blocks/CU, same footprint as before).
// Schedule per step (T3 minimum-2-phase + T14 A-split):
//   issue A-loads(t+1)->regs, B-DMA(t+1)->buf[cur^1]   (in flight)
//   ds_read frags buf[cur]; MFMA                        (hides load latency)
//   convert+ds_write A(t+1)->buf[cur^1]                 (vmcnt waits A only)
//   __syncthreads()                                     (ONE barrier/step)
// vs previous shape which drained vmcnt(0) BEFORE every MFMA phase.
// ---------------------------------------------------------------------------
#define MB_A0 0       // [32][64] bf16 swizzled, 4096 B
#define MB_A1 4096
#define MB_B0 8192    // [256][64] bf16, 32768 B
#define MB_B1 40960

__global__ __launch_bounds__(256) void gcn_main_kernel(const float* __restrict__ adj,
                                                       const uint16_t* __restrict__ spt,
                                                       const float* __restrict__ bias,
                                                       float* __restrict__ out) {
  __shared__ __align__(16) unsigned char smem[73728];
  const int t = threadIdx.x, lane = t & 63, w = t >> 6;
  const int r = lane & 15, q = lane >> 4;
  const int bb = blockIdx.x & 7;             // batch -> XCD affinity (spt[bb] L2-resident)
  const int n0 = (blockIdx.x >> 3) * 32;     // n-tile
  const float* adjb = adj + ((size_t)bb * 2048 + n0) * 2048;
  const uint16_t* sptb = spt + (size_t)bb * 2048;

  // A staging coords: 32 rows x 8 chunks (16B) = 256 ids, one per thread
  const int aRow = t >> 3, aC = t & 7;
  const float* aP = adjb + (size_t)aRow * 2048 + aC * 8;
  const unsigned aOff = aRow * 128 + ((aC ^ (aRow & 7)) << 4);

  // prologue: stage tile 0 into buf 0
  {
    const f32x4 v0 = *(const f32x4*)(aP);
    const f32x4 v1 = *(const f32x4*)(aP + 4);
#pragma unroll
    for (int j = 0; j < 8; ++j) {            // B: 256 rows x 8 chunks = 2048 ids
      const int id = j * 256 + t, row = id >> 3, c = id & 7;
      gload_lds16(sptb + (size_t)row * 16384 + c * 8,
                  smem + MB_B0 + (size_t)(j * 256 + w * 64) * 16);
    }
    uint4 u;
    u.x = (uint32_t)f2bf(v0.x) | ((uint32_t)f2bf(v0.y) << 16);
    u.y = (uint32_t)f2bf(v0.z) | ((uint32_t)f2bf(v0.w) << 16);
    u.z = (uint32_t)f2bf(v1.x) | ((uint32_t)f2bf(v1.y) << 16);
    u.w = (uint32_t)f2bf(v1.z) | ((uint32_t)f2bf(v1.w) << 16);
    *(uint4*)(smem + MB_A0 + aOff) = u;
  }
  __syncthreads();

  f32x4 acc[2][4] = {};
  for (int kt = 0; kt < 32; ++kt) {
    const int cur = kt & 1;
    const unsigned aCur = cur ? MB_A1 : MB_A0;
    const unsigned bCur = cur ? MB_B1 : MB_B0;
    const unsigned aNxt = cur ? MB_A0 : MB_A1;
    const unsigned bNxt = cur ? MB_B0 : MB_B1;
    const int k1 = (kt + 1) * 64;
    const bool pf = (kt < 31);

    // issue next-tile loads BEFORE compute: they fly under the MFMA phase
    f32x4 v0, v1;
    if (pf) {
      v0 = *(const f32x4*)(aP + k1);
      v1 = *(const f32x4*)(aP + k1 + 4);
#pragma unroll
      for (int j = 0; j < 8; ++j) {
        const int id = j * 256 + t, row = id >> 3, c = id & 7;
        gload_lds16(sptb + (size_t)row * 16384 + k1 + c * 8,
                    smem + bNxt + (size_t)(j * 256 + w * 64) * 16);
      }
    }

    // compute current tile from buf[cur]
#pragma unroll
    for (int h = 0; h < 2; ++h) {            // 2 k-halves of 32 each
      short8 av[2], bv[4];
      const int pc = (((h * 4 + q) ^ (r & 7)) << 4);  // XOR stays in low 3 bits
#pragma unroll
      for (int mi = 0; mi < 2; ++mi)
        av[mi] = *(const short8*)(smem + aCur + (16 * mi + r) * 128 + pc);
#pragma unroll
      for (int ni = 0; ni < 4; ++ni)
        bv[ni] = *(const short8*)(smem + bCur + (w * 64 + 16 * ni + r) * 128 + pc);
#pragma unroll
      for (int mi = 0; mi < 2; ++mi)
#pragma unroll
        for (int ni = 0; ni < 4; ++ni)
          acc[mi][ni] = __builtin_amdgcn_mfma_f32_16x16x32_bf16(av[mi], bv[ni],
                                                                acc[mi][ni], 0, 0, 0);
    }

    // late half of A-stage: convert+write after MFMA (waits only A's vmcnt;
    // B-DMAs stay in flight until the barrier's drain)
    if (pf) {
      uint4 u;
      u.x = (uint32_t)f2bf(v0.x) | ((uint32_t)f2bf(v0.y) << 16);
      u.y = (uint32_t)f2bf(v0.z) | ((uint32_t)f2bf(v0.w) << 16);
      u.z = (uint32_t)f2bf(v1.x) | ((uint32_t)f2bf(v1.y) << 16);
      u.w = (uint32_t)f2bf(v1.z) | ((uint32_t)f2bf(v1.w) << 16);
      *(uint4*)(smem + aNxt + aOff) = u;
    }
    __syncthreads();                         // ONE barrier/step: drains DMA + ds_write
  }

  // epilogue: +bias, relu, fp32 store
#pragma unroll
  for (int ni = 0; ni < 4; ++ni) {
    const int o = w * 64 + 16 * ni + r;      // C col = N = o
    const float bs = bias[o];
#pragma unroll
    for (int mi = 0; mi < 2; ++mi)
#pragma unroll
      for (int reg = 0; reg < 4; ++reg) {
        const int n = n0 + 16 * mi + 4 * q + reg;  // C row = M = n
        out[((size_t)bb * 2048 + n) * 256 + o] = fmaxf(acc[mi][ni][reg] + bs, 0.0f);
      }
  }
}

// ---------------------------------------------------------------------------
extern "C" void kernel_launch(void* const* d_in, const int* in_sizes, int n_in,
                              void* d_out, int out_size, void* d_ws, size_t ws_size,
                              hipStream_t stream) {
  const float* x      = (const float*)d_in[0];  // [8,2048,256]
  const float* adj    = (const float*)d_in[1];  // [8,2048,2048]
  const float* weight = (const float*)d_in[2];  // [256,256]
  const float* bias   = (const float*)d_in[3];  // [256]
  float* out = (float*)d_out;                   // [8,2048,256]

  uint16_t* dwT = (uint16_t*)d_ws;                          // 128 KB
  uint16_t* spt = (uint16_t*)((char*)d_ws + 131072);        // 8 MB

  hipLaunchKernelGGL(quant_kernel,    dim3(256),  dim3(256), 0, stream, weight, dwT);
  hipLaunchKernelGGL(support_kernel,  dim3(1024), dim3(256), 0, stream, x, dwT, spt);
  hipLaunchKernelGGL(gcn_main_kernel, dim3(512),  dim3(256), 0, stream, adj, spt, bias, out);
}